// Round 1
// baseline (317.839 us; speedup 1.0000x reference)
//
#include <hip/hip_runtime.h>

#define HWSZ 4096
#define NTRI 136
#define NSTAT 152
#define NINST 512
#define GCNT 16
#define EPSW 1e-5f

typedef float v2f __attribute__((ext_vector_type(2)));
typedef float v4f __attribute__((ext_vector_type(4)));

// ---------------------------------------------------------------------------
// K1: per-instance stats, TRIANGLE-SPLIT across 2 blocks per instance.
//   block 2b+0 (half A): s1[16] + cov rows c=0..3   (tri 0..57)  -> out [0..73]
//   block 2b+1 (half B): cov rows c=4..15           (tri 58..135)-> out [74..151]
// Output layout of the 152-float stats row is IDENTICAL to the fused version
// (s1 then tri in row-major order), so K2/K3 are unchanged.
//
// Why: previous version was latency-bound (Occ 19.6% = grid-limited 2 blk/CU,
// VALUBusy 15%, effective read BW 1.54 TB/s of ~2.6 achievable). 136 accums
// blocked any residency increase. Halving accums (74/78) fits the 128-VGPR cap
// of __launch_bounds__(256,4) -> 4 blk/CU resident, 2x waves, 2x MLP.
//
// CRITICAL register discipline (history of this kernel):
//  - position loop = "#pragma unroll 1"; EVERY loop indexing s1/s2 = full
//    unroll (dynamic indexing demotes the array to scratch: VGPR=124 +
//    phantom HBM writes + 2x slowdown).
//  - spill tripwire: WRITE_SIZE for this dispatch must stay ~304 KB.
// ---------------------------------------------------------------------------
__global__ __launch_bounds__(256, 4) void k_inst_stats(const float* __restrict__ x,
                                                       float* __restrict__ inst_stats) {
  const int bb = blockIdx.x;
  const int b = bb >> 1;      // instance
  const int half = bb & 1;    // triangle half (block-uniform branch)
  const int t = threadIdx.x;
  const int lane = t & 63;
  const int wv = t >> 6;
  const v2f* xb = (const v2f*)x + (size_t)b * 16 * 2048;

  __shared__ float red[4 * 78];

  if (half == 0) {
    // ---- half A: s1 + triangle rows c=0..3 (58 pairs) ----
    float s1[16];
    float s2[58];
#pragma unroll
    for (int i = 0; i < 16; ++i) s1[i] = 0.f;
#pragma unroll
    for (int i = 0; i < 58; ++i) s2[i] = 0.f;

#pragma unroll 1
    for (int k = 0; k < 8; ++k) {
      const int f = t + k * 256;  // float2 index within a 2048-float2 channel row
      v2f v[16];
#pragma unroll
      for (int d = 0; d < 16; ++d) v[d] = xb[d * 2048 + f];
#pragma unroll
      for (int c = 0; c < 16; ++c) s1[c] += v[c].x + v[c].y;
      int tri = 0;
#pragma unroll
      for (int c = 0; c < 4; ++c) {
#pragma unroll
        for (int d = c; d < 16; ++d) {
          s2[tri] += v[c].x * v[d].x + v[c].y * v[d].y;
          ++tri;
        }
      }
    }

    // wave shuffle reduce (fully unrolled), then cross-wave via LDS
#pragma unroll
    for (int q = 0; q < 16; ++q) {
      float v = s1[q];
#pragma unroll
      for (int off = 32; off > 0; off >>= 1) v += __shfl_down(v, off);
      if (lane == 0) red[wv * 78 + q] = v;
    }
#pragma unroll
    for (int q = 0; q < 58; ++q) {
      float v = s2[q];
#pragma unroll
      for (int off = 32; off > 0; off >>= 1) v += __shfl_down(v, off);
      if (lane == 0) red[wv * 78 + 16 + q] = v;
    }
    __syncthreads();
    if (t < 74) {
      inst_stats[(size_t)b * NSTAT + t] =
          red[t] + red[78 + t] + red[156 + t] + red[234 + t];
    }
  } else {
    // ---- half B: triangle rows c=4..15 (78 pairs), channels 4..15 only ----
    float s2[78];
#pragma unroll
    for (int i = 0; i < 78; ++i) s2[i] = 0.f;

#pragma unroll 1
    for (int k = 0; k < 8; ++k) {
      const int f = t + k * 256;
      v2f v[12];
#pragma unroll
      for (int d = 0; d < 12; ++d) v[d] = xb[(d + 4) * 2048 + f];
      int tri = 0;
#pragma unroll
      for (int c = 0; c < 12; ++c) {
#pragma unroll
        for (int d = c; d < 12; ++d) {
          s2[tri] += v[c].x * v[d].x + v[c].y * v[d].y;
          ++tri;
        }
      }
    }

#pragma unroll
    for (int q = 0; q < 78; ++q) {
      float v = s2[q];
#pragma unroll
      for (int off = 32; off > 0; off >>= 1) v += __shfl_down(v, off);
      if (lane == 0) red[wv * 78 + q] = v;
    }
    __syncthreads();
    if (t < 78) {
      inst_stats[(size_t)b * NSTAT + 74 + t] =
          red[t] + red[78 + t] + red[156 + t] + red[234 + t];
    }
  }
}

// ---------------------------------------------------------------------------
// K2: group (batch-whitening) stats: sum instance stats over N=32 per group.
// ---------------------------------------------------------------------------
__global__ __launch_bounds__(192) void k_group(const float* __restrict__ inst_stats,
                                               float* __restrict__ grp_stats) {
  const int g = blockIdx.x;
  const int t = threadIdx.x;
  if (t < NSTAT) {
    float s = 0.f;
    for (int n = 0; n < 32; ++n) s += inst_stats[(size_t)(n * GCNT + g) * NSTAT + t];
    grp_stats[(size_t)g * NSTAT + t] = s;
  }
}

// ---------------------------------------------------------------------------
// K3: per-instance mixing + Newton-Schulz. One block (256 thr) per instance;
// thread t owns matrix element (row=t>>4, col=t&15).
// Outputs folded affine transform: y = W' x + o.
// ---------------------------------------------------------------------------
__global__ __launch_bounds__(256) void k_newton(const float* __restrict__ inst_stats,
                                                const float* __restrict__ grp_stats,
                                                const float* __restrict__ swm,
                                                const float* __restrict__ swv,
                                                const float* __restrict__ weight,
                                                const float* __restrict__ bias,
                                                float* __restrict__ apply_wm,
                                                float* __restrict__ apply_ofs) {
  const int b = blockIdx.x;
  const int g = b & 15;
  const int t = threadIdx.x;
  const int r = t >> 4;
  const int c = t & 15;

  __shared__ float P[256], Qm[256], Rm[256], CN[256], Wl[256];
  __shared__ float Mm[16], Mi[16], Mb[16];

  float a0 = swm[0], a1 = swm[1];
  float mx = fmaxf(a0, a1);
  float e0 = expf(a0 - mx), e1 = expf(a1 - mx);
  const float mw0 = e0 / (e0 + e1), mw1 = e1 / (e0 + e1);
  a0 = swv[0]; a1 = swv[1];
  mx = fmaxf(a0, a1);
  e0 = expf(a0 - mx); e1 = expf(a1 - mx);
  const float vw0 = e0 / (e0 + e1), vw1 = e1 / (e0 + e1);

  const float inv_hw = 1.0f / (float)HWSZ;
  const float inv_nhw = 1.0f / (32.0f * (float)HWSZ);

  if (t < 16) {
    const float mi = inst_stats[(size_t)b * NSTAT + t] * inv_hw;
    const float mb = grp_stats[(size_t)g * NSTAT + t] * inv_nhw;
    Mi[t] = mi;
    Mb[t] = mb;
    Mm[t] = mw0 * mb + mw1 * mi;
  }
  __syncthreads();

  const int cmin = (r < c) ? r : c;
  const int cmax = (r < c) ? c : r;
  const int tri = 15 * cmin - (cmin * (cmin - 1)) / 2 + cmax + 16;
  const float cin = inst_stats[(size_t)b * NSTAT + tri] * inv_hw - Mi[r] * Mi[c];
  const float cbn = grp_stats[(size_t)g * NSTAT + tri] * inv_nhw - Mb[r] * Mb[c];
  float cov = vw0 * cbn + vw1 * cin + ((r == c) ? EPSW : 0.0f);

  Qm[t] = cov;
  __syncthreads();
  float trace = 0.f;
#pragma unroll
  for (int i = 0; i < 16; ++i) trace += Qm[i * 16 + i];
  const float rTr = 1.0f / trace;

  CN[t] = cov * rTr;
  P[t] = (r == c) ? 1.0f : 0.0f;
  __syncthreads();

  for (int it = 0; it < 5; ++it) {
    float q = 0.f;
#pragma unroll
    for (int k = 0; k < 16; ++k) q += P[r * 16 + k] * P[k * 16 + c];
    Qm[t] = q;
    __syncthreads();
    float rr = 0.f;
#pragma unroll
    for (int k = 0; k < 16; ++k) rr += Qm[r * 16 + k] * P[k * 16 + c];
    Rm[t] = rr;
    __syncthreads();
    float tt = 0.f;
#pragma unroll
    for (int k = 0; k < 16; ++k) tt += Rm[r * 16 + k] * CN[k * 16 + c];
    const float np = 1.5f * P[t] - 0.5f * tt;
    __syncthreads();
    P[t] = np;
    __syncthreads();
  }

  const float sr = sqrtf(rTr);
  const float wel = P[t] * sr * weight[g * 16 + r];
  Wl[t] = wel;
  apply_wm[(size_t)b * 256 + t] = wel;
  __syncthreads();
  if (t < 16) {
    float acc = 0.f;
#pragma unroll
    for (int d = 0; d < 16; ++d) acc += Wl[t * 16 + d] * Mm[d];
    apply_ofs[(size_t)b * 16 + t] = bias[g * 16 + t] - acc;
  }
}

// ---------------------------------------------------------------------------
// K4: apply y = W' x + o. 4 blocks per instance (2048 blocks); each thread
// owns ONE float4 column (all 16 channels). ~100 live VGPRs -> 4 waves/EU.
// ---------------------------------------------------------------------------
__global__ __launch_bounds__(256, 4) void k_apply(const float* __restrict__ x,
                                                  const float* __restrict__ apply_wm,
                                                  const float* __restrict__ apply_ofs,
                                                  float* __restrict__ y) {
  const int bb = blockIdx.x;
  const int b = bb >> 2;      // instance
  const int chunk = bb & 3;   // position chunk
  const int t = threadIdx.x;

  __shared__ float Wl[256];
  __shared__ float Ol[16];
  Wl[t] = apply_wm[(size_t)b * 256 + t];
  if (t < 16) Ol[t] = apply_ofs[(size_t)b * 16 + t];
  __syncthreads();

  const v4f* xb = (const v4f*)x + (size_t)b * 16 * 1024;  // 1024 v4f per channel row
  v4f* yb = (v4f*)y + (size_t)b * 16 * 1024;
  const int f = chunk * 256 + t;  // v4f index within channel row

  v4f v[16];
#pragma unroll
  for (int d = 0; d < 16; ++d) v[d] = xb[d * 1024 + f];

#pragma unroll
  for (int cch = 0; cch < 16; ++cch) {
    v4f acc = Ol[cch];
#pragma unroll
    for (int d = 0; d < 16; ++d) acc += Wl[cch * 16 + d] * v[d];
    yb[cch * 1024 + f] = acc;
  }
}

// ---------------------------------------------------------------------------
extern "C" void kernel_launch(void* const* d_in, const int* in_sizes, int n_in,
                              void* d_out, int out_size, void* d_ws, size_t ws_size,
                              hipStream_t stream) {
  const float* x = (const float*)d_in[0];
  const float* swm = (const float*)d_in[1];
  const float* swv = (const float*)d_in[2];
  const float* weight = (const float*)d_in[3];
  const float* bias = (const float*)d_in[4];
  float* out = (float*)d_out;

  float* ws = (float*)d_ws;
  float* inst = ws;                          // 512*152
  float* grp = inst + (size_t)NINST * NSTAT; // 16*152
  float* awm = grp + (size_t)GCNT * NSTAT;   // 512*256
  float* aofs = awm + (size_t)NINST * 256;   // 512*16

  k_inst_stats<<<NINST * 2, 256, 0, stream>>>(x, inst);
  k_group<<<GCNT, 192, 0, stream>>>(inst, grp);
  k_newton<<<NINST, 256, 0, stream>>>(inst, grp, swm, swv, weight, bias, awm, aofs);
  k_apply<<<NINST * 4, 256, 0, stream>>>(x, awm, aofs, out);
}

// Round 2
// 297.579 us; speedup vs baseline: 1.0681x; 1.0681x over previous
//
#include <hip/hip_runtime.h>

#define HWSZ 4096
#define NTRI 136
#define NSTAT 152
#define NINST 512
#define GCNT 16
#define EPSW 1e-5f

typedef float v2f __attribute__((ext_vector_type(2)));
typedef float v4f __attribute__((ext_vector_type(4)));

// ---------------------------------------------------------------------------
// K1: per-instance stats, TRIANGLE-SPLIT across 2 blocks per instance.
//   block 2b+0 (half A): s1[16] + cov rows c=0..3   (tri 0..57)  -> out [0..73]
//   block 2b+1 (half B): cov rows c=4..15           (tri 58..135)-> out [74..151]
//
// REGISTER CAP HISTORY (do not regress):
//  - (256,2) fused 152-accum version: VGPR=124+AGPR, 2 blk/CU, latency-bound
//    at 87 us (VALUBusy 15%, eff BW 0.77 TB/s).
//  - (256,4) split version: unified VGPR+AGPR cap = 128/wave -> half A's ~120
//    live regs spilled (WRITE_SIZE 304 KB -> 87 MB, dur 100 us). 128 is NOT
//    enough for 74 accums + 16 v2f loads.
//  - (256,3) [THIS]: cap ~168/wave, 3 blk/CU = 12 waves/CU. Half A ~118 live,
//    half B ~114 live -> fits with slack. Round-1 measured 2.3 TB/s deliverable
//    at this occupancy -> 112 MB logical reads ~ 50 us.
//  Spill tripwire: WRITE_SIZE for this dispatch must stay ~304 KB.
//
// CRITICAL register discipline:
//  - position loop = "#pragma unroll 1"; EVERY loop indexing s1/s2 = full
//    unroll (dynamic indexing demotes the array to scratch).
// ---------------------------------------------------------------------------
__global__ __launch_bounds__(256, 3) void k_inst_stats(const float* __restrict__ x,
                                                       float* __restrict__ inst_stats) {
  const int bb = blockIdx.x;
  const int b = bb >> 1;      // instance
  const int half = bb & 1;    // triangle half (block-uniform branch)
  const int t = threadIdx.x;
  const int lane = t & 63;
  const int wv = t >> 6;
  const v2f* xb = (const v2f*)x + (size_t)b * 16 * 2048;

  __shared__ float red[4 * 78];

  if (half == 0) {
    // ---- half A: s1 + triangle rows c=0..3 (58 pairs) ----
    float s1[16];
    float s2[58];
#pragma unroll
    for (int i = 0; i < 16; ++i) s1[i] = 0.f;
#pragma unroll
    for (int i = 0; i < 58; ++i) s2[i] = 0.f;

#pragma unroll 1
    for (int k = 0; k < 8; ++k) {
      const int f = t + k * 256;  // float2 index within a 2048-float2 channel row
      v2f v[16];
#pragma unroll
      for (int d = 0; d < 16; ++d) v[d] = xb[d * 2048 + f];
#pragma unroll
      for (int c = 0; c < 16; ++c) s1[c] += v[c].x + v[c].y;
      int tri = 0;
#pragma unroll
      for (int c = 0; c < 4; ++c) {
#pragma unroll
        for (int d = c; d < 16; ++d) {
          s2[tri] += v[c].x * v[d].x + v[c].y * v[d].y;
          ++tri;
        }
      }
    }

    // wave shuffle reduce (fully unrolled), then cross-wave via LDS
#pragma unroll
    for (int q = 0; q < 16; ++q) {
      float v = s1[q];
#pragma unroll
      for (int off = 32; off > 0; off >>= 1) v += __shfl_down(v, off);
      if (lane == 0) red[wv * 78 + q] = v;
    }
#pragma unroll
    for (int q = 0; q < 58; ++q) {
      float v = s2[q];
#pragma unroll
      for (int off = 32; off > 0; off >>= 1) v += __shfl_down(v, off);
      if (lane == 0) red[wv * 78 + 16 + q] = v;
    }
    __syncthreads();
    if (t < 74) {
      inst_stats[(size_t)b * NSTAT + t] =
          red[t] + red[78 + t] + red[156 + t] + red[234 + t];
    }
  } else {
    // ---- half B: triangle rows c=4..15 (78 pairs), channels 4..15 only ----
    float s2[78];
#pragma unroll
    for (int i = 0; i < 78; ++i) s2[i] = 0.f;

#pragma unroll 1
    for (int k = 0; k < 8; ++k) {
      const int f = t + k * 256;
      v2f v[12];
#pragma unroll
      for (int d = 0; d < 12; ++d) v[d] = xb[(d + 4) * 2048 + f];
      int tri = 0;
#pragma unroll
      for (int c = 0; c < 12; ++c) {
#pragma unroll
        for (int d = c; d < 12; ++d) {
          s2[tri] += v[c].x * v[d].x + v[c].y * v[d].y;
          ++tri;
        }
      }
    }

#pragma unroll
    for (int q = 0; q < 78; ++q) {
      float v = s2[q];
#pragma unroll
      for (int off = 32; off > 0; off >>= 1) v += __shfl_down(v, off);
      if (lane == 0) red[wv * 78 + q] = v;
    }
    __syncthreads();
    if (t < 78) {
      inst_stats[(size_t)b * NSTAT + 74 + t] =
          red[t] + red[78 + t] + red[156 + t] + red[234 + t];
    }
  }
}

// ---------------------------------------------------------------------------
// K3: per-instance mixing + Newton-Schulz, with K2 (group stats) FUSED in:
// each block recomputes its group's 152 sums from inst_stats into LDS
// (311 KB buffer is L2-resident; 152 threads x 32 independent loads).
// One block (256 thr) per instance; thread t owns element (row=t>>4, col=t&15).
// Outputs folded affine transform: y = W' x + o.
// ---------------------------------------------------------------------------
__global__ __launch_bounds__(256) void k_newton(const float* __restrict__ inst_stats,
                                                const float* __restrict__ swm,
                                                const float* __restrict__ swv,
                                                const float* __restrict__ weight,
                                                const float* __restrict__ bias,
                                                float* __restrict__ apply_wm,
                                                float* __restrict__ apply_ofs) {
  const int b = blockIdx.x;
  const int g = b & 15;
  const int t = threadIdx.x;
  const int r = t >> 4;
  const int c = t & 15;

  __shared__ float P[256], Qm[256], Rm[256], CN[256], Wl[256];
  __shared__ float Mm[16], Mi[16], Mb[16];
  __shared__ float Gs[NSTAT];

  // fused K2: group sums over the 32 instances of this group
  if (t < NSTAT) {
    float s = 0.f;
#pragma unroll 8
    for (int n = 0; n < 32; ++n) s += inst_stats[(size_t)(n * GCNT + g) * NSTAT + t];
    Gs[t] = s;
  }

  float a0 = swm[0], a1 = swm[1];
  float mx = fmaxf(a0, a1);
  float e0 = expf(a0 - mx), e1 = expf(a1 - mx);
  const float mw0 = e0 / (e0 + e1), mw1 = e1 / (e0 + e1);
  a0 = swv[0]; a1 = swv[1];
  mx = fmaxf(a0, a1);
  e0 = expf(a0 - mx); e1 = expf(a1 - mx);
  const float vw0 = e0 / (e0 + e1), vw1 = e1 / (e0 + e1);

  const float inv_hw = 1.0f / (float)HWSZ;
  const float inv_nhw = 1.0f / (32.0f * (float)HWSZ);

  __syncthreads();

  if (t < 16) {
    const float mi = inst_stats[(size_t)b * NSTAT + t] * inv_hw;
    const float mb = Gs[t] * inv_nhw;
    Mi[t] = mi;
    Mb[t] = mb;
    Mm[t] = mw0 * mb + mw1 * mi;
  }
  __syncthreads();

  const int cmin = (r < c) ? r : c;
  const int cmax = (r < c) ? c : r;
  const int tri = 15 * cmin - (cmin * (cmin - 1)) / 2 + cmax + 16;
  const float cin = inst_stats[(size_t)b * NSTAT + tri] * inv_hw - Mi[r] * Mi[c];
  const float cbn = Gs[tri] * inv_nhw - Mb[r] * Mb[c];
  float cov = vw0 * cbn + vw1 * cin + ((r == c) ? EPSW : 0.0f);

  Qm[t] = cov;
  __syncthreads();
  float trace = 0.f;
#pragma unroll
  for (int i = 0; i < 16; ++i) trace += Qm[i * 16 + i];
  const float rTr = 1.0f / trace;

  CN[t] = cov * rTr;
  P[t] = (r == c) ? 1.0f : 0.0f;
  __syncthreads();

  for (int it = 0; it < 5; ++it) {
    float q = 0.f;
#pragma unroll
    for (int k = 0; k < 16; ++k) q += P[r * 16 + k] * P[k * 16 + c];
    Qm[t] = q;
    __syncthreads();
    float rr = 0.f;
#pragma unroll
    for (int k = 0; k < 16; ++k) rr += Qm[r * 16 + k] * P[k * 16 + c];
    Rm[t] = rr;
    __syncthreads();
    float tt = 0.f;
#pragma unroll
    for (int k = 0; k < 16; ++k) tt += Rm[r * 16 + k] * CN[k * 16 + c];
    const float np = 1.5f * P[t] - 0.5f * tt;
    __syncthreads();
    P[t] = np;
    __syncthreads();
  }

  const float sr = sqrtf(rTr);
  const float wel = P[t] * sr * weight[g * 16 + r];
  Wl[t] = wel;
  apply_wm[(size_t)b * 256 + t] = wel;
  __syncthreads();
  if (t < 16) {
    float acc = 0.f;
#pragma unroll
    for (int d = 0; d < 16; ++d) acc += Wl[t * 16 + d] * Mm[d];
    apply_ofs[(size_t)b * 16 + t] = bias[g * 16 + t] - acc;
  }
}

// ---------------------------------------------------------------------------
// K4: apply y = W' x + o. 4 blocks per instance (2048 blocks); each thread
// owns ONE float4 column (all 16 channels). ~100 live VGPRs -> 4 waves/EU.
// ---------------------------------------------------------------------------
__global__ __launch_bounds__(256, 4) void k_apply(const float* __restrict__ x,
                                                  const float* __restrict__ apply_wm,
                                                  const float* __restrict__ apply_ofs,
                                                  float* __restrict__ y) {
  const int bb = blockIdx.x;
  const int b = bb >> 2;      // instance
  const int chunk = bb & 3;   // position chunk
  const int t = threadIdx.x;

  __shared__ float Wl[256];
  __shared__ float Ol[16];
  Wl[t] = apply_wm[(size_t)b * 256 + t];
  if (t < 16) Ol[t] = apply_ofs[(size_t)b * 16 + t];
  __syncthreads();

  const v4f* xb = (const v4f*)x + (size_t)b * 16 * 1024;  // 1024 v4f per channel row
  v4f* yb = (v4f*)y + (size_t)b * 16 * 1024;
  const int f = chunk * 256 + t;  // v4f index within channel row

  v4f v[16];
#pragma unroll
  for (int d = 0; d < 16; ++d) v[d] = xb[d * 1024 + f];

#pragma unroll
  for (int cch = 0; cch < 16; ++cch) {
    v4f acc = Ol[cch];
#pragma unroll
    for (int d = 0; d < 16; ++d) acc += Wl[cch * 16 + d] * v[d];
    yb[cch * 1024 + f] = acc;
  }
}

// ---------------------------------------------------------------------------
extern "C" void kernel_launch(void* const* d_in, const int* in_sizes, int n_in,
                              void* d_out, int out_size, void* d_ws, size_t ws_size,
                              hipStream_t stream) {
  const float* x = (const float*)d_in[0];
  const float* swm = (const float*)d_in[1];
  const float* swv = (const float*)d_in[2];
  const float* weight = (const float*)d_in[3];
  const float* bias = (const float*)d_in[4];
  float* out = (float*)d_out;

  float* ws = (float*)d_ws;
  float* inst = ws;                          // 512*152
  float* awm = inst + (size_t)NINST * NSTAT; // 512*256
  float* aofs = awm + (size_t)NINST * 256;   // 512*16

  k_inst_stats<<<NINST * 2, 256, 0, stream>>>(x, inst);
  k_newton<<<NINST, 256, 0, stream>>>(inst, swm, swv, weight, bias, awm, aofs);
  k_apply<<<NINST * 4, 256, 0, stream>>>(x, awm, aofs, out);
}